// Round 8
// baseline (137.196 us; speedup 1.0000x reference)
//
#include <hip/hip_runtime.h>
#include <math.h>

#define NROWS 4096
#define NCLS  32000
#define VEC_PER_ROW (NCLS / 4)     // 8000 float4s per row
#define BLK 1024
#define NV  8                      // 1024*8 = 8192 >= 8000
#define TAILT (VEC_PER_ROW - (NV - 1) * BLK)   // 832
#define NBLOCKS 256                // persistent: exactly 1 block/CU
#define ROWS_PER_BLK (NROWS / NBLOCKS)         // 16
#define EPSF 1e-6f
#define LN2  0.69314718055994530942f
#define L2E  1.44269504088896340736f

// ln(4095/4096), precomputed in double precision
#define LNBETA (-2.4417042724800387e-4f)
// (1 - beta) = 1/4096 exactly
#define WNUM 2.44140625e-4f

#define ROWS_PER_FBLK 16           // finalize: 16 waves/block, one row per wave

__device__ __forceinline__ float max4(float4 v) {
    return fmaxf(fmaxf(v.x, v.y), fmaxf(v.z, v.w));
}
__device__ __forceinline__ float sum4(float4 v) {
    return (v.x + v.y) + (v.z + v.w);
}

__device__ __forceinline__ void load_row(const float4* __restrict__ pred4, int row,
                                         int tid, bool lv, float4 (&x)[NV])
{
    const float4* rp = pred4 + (size_t)row * VEC_PER_ROW;
#pragma unroll
    for (int k = 0; k < NV - 1; ++k) x[k] = rp[tid + k * BLK];
    if (lv) x[NV - 1] = rp[tid + (NV - 1) * BLK];
    else    x[NV - 1] = make_float4(-1e30f, -1e30f, -1e30f, -1e30f);
}

__device__ __forceinline__ void compute_row(const float4 (&x)[NV], bool lv, int row,
                                            int tid, int wid, int lane,
                                            float* sm, float* ss,
                                            float* r0, float* r1, float* r2, float* r3,
                                            float* __restrict__ focal_out)
{
    // ---- pass A: per-thread max + sum ----
    float m = -1e30f, s1 = 0.0f;
#pragma unroll
    for (int i = 0; i < NV - 1; ++i) { m = fmaxf(m, max4(x[i])); s1 += sum4(x[i]); }
    m = fmaxf(m, max4(x[NV - 1]));
    if (lv) s1 += sum4(x[NV - 1]);

#pragma unroll
    for (int off = 32; off > 0; off >>= 1) {
        m  = fmaxf(m, __shfl_xor(m, off));
        s1 += __shfl_xor(s1, off);
    }
    if (lane == 0) { sm[wid] = m; ss[wid] = s1; }
    __syncthreads();
    if (tid < 64) {
        float mm = (tid < 16) ? sm[tid] : -1e30f;
        float s  = (tid < 16) ? ss[tid] : 0.0f;
#pragma unroll
        for (int off = 8; off > 0; off >>= 1) {
            mm = fmaxf(mm, __shfl_xor(mm, off));
            s += __shfl_xor(s, off);
        }
        if (tid == 0) { sm[0] = mm; ss[0] = s; }
    }
    __syncthreads();
    const float M  = sm[0];
    const float S1 = ss[0];

    // ---- pass B (registers only) ----
    float Z = 0.f, A = 0.f, Z2 = 0.f, A2 = 0.f;
#pragma unroll
    for (int i = 0; i < NV; ++i) {
        float vals[4] = {x[i].x, x[i].y, x[i].z, x[i].w};
#pragma unroll
        for (int j = 0; j < 4; ++j) {
            float t = vals[j] - M;                        // masked lanes: finite sentinel
            float e = exp2f(t * L2E);                     // masked -> 0
            Z += e;
            A = fmaf(e, t, A);
            float e2 = e * e;
            Z2 += e2;
            A2 = fmaf(e2, t, A2);
        }
    }

#pragma unroll
    for (int off = 32; off > 0; off >>= 1) {
        Z  += __shfl_xor(Z,  off);
        A  += __shfl_xor(A,  off);
        Z2 += __shfl_xor(Z2, off);
        A2 += __shfl_xor(A2, off);
    }
    if (lane == 0) { r0[wid] = Z; r1[wid] = A; r2[wid] = Z2; r3[wid] = A2; }
    __syncthreads();
    if (tid < 64) {
        float a = (tid < 16) ? r0[tid] : 0.f;
        float b = (tid < 16) ? r1[tid] : 0.f;
        float c = (tid < 16) ? r2[tid] : 0.f;
        float d = (tid < 16) ? r3[tid] : 0.f;
#pragma unroll
        for (int off = 8; off > 0; off >>= 1) {
            a += __shfl_xor(a, off);
            b += __shfl_xor(b, off);
            c += __shfl_xor(c, off);
            d += __shfl_xor(d, off);
        }
        if (tid == 0) {
            float lnZ  = log2f(a) * LN2;
            float invZ = 1.0f / a;
            float T = S1 - (float)NCLS * M;
            float focal = (T - (float)NCLS * lnZ)
                        - 2.0f * (b * invZ - lnZ)
                        + (d - lnZ * c) * (invZ * invZ);
            focal_out[row] = focal;
        }
    }
    __syncthreads();   // protect r0..r3 reads before next row's writes
}

// Persistent double-buffered focal: 256 blocks (1/CU), 16 rows each.
// While row i is computed from buffer A, row i+1's loads fill buffer B —
// the memory pipe never drains across compute/reduce phases.
__global__ __launch_bounds__(BLK, 4) void focal_kernel(const float* __restrict__ pred,
                                                       float* __restrict__ focal_out,
                                                       float* __restrict__ out)
{
    const int bid  = blockIdx.x;
    const int tid  = threadIdx.x;
    const int wid  = tid >> 6;
    const int lane = tid & 63;
    const bool lv  = tid < TAILT;
    if (bid == 0 && tid == 0) out[0] = 0.0f;   // zero accumulator for finalize

    __shared__ float sm[16], ss[16], r0[16], r1[16], r2[16], r3[16];

    const float4* pred4 = reinterpret_cast<const float4*>(pred);

    float4 xa[NV], xb[NV];
    load_row(pred4, bid, tid, lv, xa);         // row for i=0

    for (int i = 0; i < ROWS_PER_BLK; i += 2) {
        const int rowA = bid + NBLOCKS * i;
        const int rowB = bid + NBLOCKS * (i + 1);
        // prefetch row i+1 into B while computing row i from A
        load_row(pred4, rowB, tid, lv, xb);
        compute_row(xa, lv, rowA, tid, wid, lane, sm, ss, r0, r1, r2, r3, focal_out);
        // prefetch row i+2 into A while computing row i+1 from B
        if (i + 2 < ROWS_PER_BLK)
            load_row(pred4, bid + NBLOCKS * (i + 2), tid, lv, xa);
        compute_row(xb, lv, rowB, tid, wid, lane, sm, ss, r0, r1, r2, r3, focal_out);
    }
}

// Parallel finalize (R7): 256 blocks x 16 waves; wave owns one row, scans all
// 4096 targets (L1/L2-resident), computes weighted contribution, one
// atomicAdd per block.
__global__ __launch_bounds__(1024) void finalize_kernel(const int* __restrict__ target,
                                                        const float* __restrict__ focal,
                                                        float* __restrict__ out)
{
    const int tid  = threadIdx.x;
    const int wid  = tid >> 6;
    const int lane = tid & 63;
    const int row  = blockIdx.x * ROWS_PER_FBLK + wid;

    const int t_row = target[row];
    const int4* tg = reinterpret_cast<const int4*>(target);
    int cnt = 0;
#pragma unroll
    for (int k = 0; k < NROWS / 4 / 64; ++k) {       // 16 int4 per lane
        int4 v = tg[lane + k * 64];
        cnt += (v.x == t_row) + (v.y == t_row) + (v.z == t_row) + (v.w == t_row);
    }
#pragma unroll
    for (int off = 32; off > 0; off >>= 1) cnt += __shfl_xor(cnt, off);

    __shared__ float part[ROWS_PER_FBLK];
    if (lane == 0) {
        float u = (float)cnt * LNBETA;       // n * ln(beta), small negative
        float denom;
        if (u > -0.25f) {
            denom = -(u * (1.f + u * (0.5f + u * (0.16666667f + u * 0.041666667f))));
        } else {
            denom = 1.f - __expf(u);
        }
        float w = WNUM / (denom + EPSF);
        part[wid] = w * (float)t_row * focal[row] * (-1.0f / (float)NROWS);
    }
    __syncthreads();
    if (tid == 0) {
        float s = 0.f;
#pragma unroll
        for (int i = 0; i < ROWS_PER_FBLK; ++i) s += part[i];
        atomicAdd(out, s);
    }
}

extern "C" void kernel_launch(void* const* d_in, const int* in_sizes, int n_in,
                              void* d_out, int out_size, void* d_ws, size_t ws_size,
                              hipStream_t stream)
{
    const float* pred  = (const float*)d_in[0];
    const int* target  = (const int*)d_in[1];
    float* out         = (float*)d_out;

    float* focal = (float*)d_ws;   // 4096 floats

    focal_kernel<<<NBLOCKS, BLK, 0, stream>>>(pred, focal, out);
    finalize_kernel<<<NROWS / ROWS_PER_FBLK, 1024, 0, stream>>>(target, focal, out);
}

// Round 9
// 100.898 us; speedup vs baseline: 1.3597x; 1.3597x over previous
//
#include <hip/hip_runtime.h>
#include <math.h>

#define NROWS 4096
#define NCLS  32000
#define VEC_PER_ROW (NCLS / 4)   // 8000 float4s per row
#define BLK 512
#define NV  16                   // float4 per thread: 512*16 = 8192 >= 8000
#define TAIL (VEC_PER_ROW - (NV - 1) * BLK)   // 320
#define EPSF 1e-6f

// ln(4095/4096), precomputed in double precision
#define LNBETA (-2.4417042724800387e-4f)
// (1 - beta) = 1/4096 exactly
#define WNUM 2.44140625e-4f

__device__ __forceinline__ float max4(float4 v) {
    return fmaxf(fmaxf(v.x, v.y), fmaxf(v.z, v.w));
}
__device__ __forceinline__ float sum4(float4 v) {
    return (v.x + v.y) + (v.z + v.w);
}

// One row per block. 512 threads * 16 float4, last vec masked for tid >= 320.
// __launch_bounds__(512,4): cap VGPR at 128 -> 2 blocks/CU so one block's
// exp-phase overlaps the other's load-phase.
// This is the measured-best structure (R2: 98.3 us). Fusing ANYTHING else in
// (target scan, atomics) regresses ~4-7 us: the compiler hoists fused loads
// into the load phase and blows past the VGPR cap (R4-R6). Persistent
// double-buffering regresses 40 us (R8).
__global__ __launch_bounds__(BLK, 4) void focal_kernel(const float* __restrict__ pred,
                                                       float* __restrict__ focal_out)
{
    const int row = blockIdx.x;
    const int tid = threadIdx.x;
    const float4* rp = reinterpret_cast<const float4*>(pred) + (size_t)row * VEC_PER_ROW;

    float4 x[NV];
#pragma unroll
    for (int i = 0; i < NV - 1; ++i) x[i] = rp[tid + i * BLK];
    const bool lv = tid < TAIL;
    if (lv) x[NV - 1] = rp[tid + (NV - 1) * BLK];
    else    x[NV - 1] = make_float4(-1e30f, -1e30f, -1e30f, -1e30f);

    // ---- pass A: per-thread max + sum ----
    float m = -1e30f, s1 = 0.0f;
#pragma unroll
    for (int i = 0; i < NV - 1; ++i) { m = fmaxf(m, max4(x[i])); s1 += sum4(x[i]); }
    m = fmaxf(m, max4(x[NV - 1]));
    if (lv) s1 += sum4(x[NV - 1]);

    // ---- block reduce (max, sum): 8 waves ----
    __shared__ float sm[8], ss[8];
#pragma unroll
    for (int off = 32; off > 0; off >>= 1) {
        m  = fmaxf(m, __shfl_xor(m, off));
        s1 += __shfl_xor(s1, off);
    }
    const int wid  = tid >> 6;
    const int lane = tid & 63;
    if (lane == 0) { sm[wid] = m; ss[wid] = s1; }
    __syncthreads();
    if (tid < 64) {
        float mm = (tid < 8) ? sm[tid] : -1e30f;
        float s  = (tid < 8) ? ss[tid] : 0.0f;
#pragma unroll
        for (int off = 4; off > 0; off >>= 1) {
            mm = fmaxf(mm, __shfl_xor(mm, off));
            s += __shfl_xor(s, off);
        }
        if (tid == 0) { sm[0] = mm; ss[0] = s; }
    }
    __syncthreads();
    const float M  = sm[0];
    const float S1 = ss[0];

    // ---- pass B (registers only): Z, A=Σe^t·t, Z2=Σe^2t, A2=Σe^2t·t ----
    float Z = 0.f, A = 0.f, Z2 = 0.f, A2 = 0.f;
#pragma unroll
    for (int i = 0; i < NV; ++i) {
        float vals[4] = {x[i].x, x[i].y, x[i].z, x[i].w};
#pragma unroll
        for (int j = 0; j < 4; ++j) {
            float t = vals[j] - M;                        // masked lanes: t ~ -1e30 (finite)
            float e = exp2f(t * 1.44269504088896340736f); // e^t ; masked -> 0
            Z += e;
            A = fmaf(e, t, A);                            // fma(0, -1e30, A) = A, safe
            float e2 = e * e;
            Z2 += e2;
            A2 = fmaf(e2, t, A2);
        }
    }

    // ---- block reduce 4 accumulators ----
    __shared__ float r0[8], r1[8], r2[8], r3[8];
#pragma unroll
    for (int off = 32; off > 0; off >>= 1) {
        Z  += __shfl_xor(Z,  off);
        A  += __shfl_xor(A,  off);
        Z2 += __shfl_xor(Z2, off);
        A2 += __shfl_xor(A2, off);
    }
    if (lane == 0) { r0[wid] = Z; r1[wid] = A; r2[wid] = Z2; r3[wid] = A2; }
    __syncthreads();
    if (tid < 64) {
        float a = (tid < 8) ? r0[tid] : 0.f;
        float b = (tid < 8) ? r1[tid] : 0.f;
        float c = (tid < 8) ? r2[tid] : 0.f;
        float d = (tid < 8) ? r3[tid] : 0.f;
#pragma unroll
        for (int off = 4; off > 0; off >>= 1) {
            a += __shfl_xor(a, off);
            b += __shfl_xor(b, off);
            c += __shfl_xor(c, off);
            d += __shfl_xor(d, off);
        }
        if (tid == 0) {
            float lnZ  = log2f(a) * 0.69314718055994530942f;
            float invZ = 1.0f / a;
            float T = S1 - (float)NCLS * M;
            // focal = Σ(1-p)^2 * logp, expanded in (t, lnZ)
            float focal = (T - (float)NCLS * lnZ)
                        - 2.0f * (b * invZ - lnZ)
                        + (d - lnZ * c) * (invZ * invZ);
            focal_out[row] = focal;
        }
    }
}

// Fused count + finalize: packed 16-bit LDS histogram (counts <= 4096 fit u16),
// 16000 u32 words = 64 KB LDS.
__global__ __launch_bounds__(1024) void finalize_kernel(const int* __restrict__ target,
                                                        const float* __restrict__ focal,
                                                        float* __restrict__ out)
{
    __shared__ unsigned int cnt[NCLS / 2];   // 64000 B
    __shared__ double rd[16];
    const int tid = threadIdx.x;

    // zero histogram
    uint4* c4 = reinterpret_cast<uint4*>(cnt);
    for (int i = tid; i < NCLS / 8; i += 1024) c4[i] = make_uint4(0u, 0u, 0u, 0u);
    __syncthreads();

    // build histogram (packed 16-bit lanes; max count 4096 < 65536, no carry-out)
    for (int b = tid; b < NROWS; b += 1024) {
        int t = target[b];
        atomicAdd(&cnt[t >> 1], 1u << ((t & 1) * 16));
    }
    __syncthreads();

    double local = 0.0;
    for (int b = tid; b < NROWS; b += 1024) {
        int t = target[b];
        int n = (int)((cnt[t >> 1] >> ((t & 1) * 16)) & 0xffffu);  // n >= 1
        float u = (float)n * LNBETA;       // u = n * ln(beta), small negative
        float denom;
        if (u > -0.25f) {
            // 1 - beta^n = -expm1(u) ~= -(u + u^2/2 + u^3/6 + u^4/24)
            denom = -(u * (1.f + u * (0.5f + u * (0.16666667f + u * 0.041666667f))));
        } else {
            denom = 1.f - __expf(u);
        }
        float w = WNUM / (denom + EPSF);
        local += (double)(w * (float)t * focal[b]);
    }

    // block reduce (double)
#pragma unroll
    for (int off = 32; off > 0; off >>= 1) local += __shfl_xor(local, off);
    const int wid = tid >> 6, lane = tid & 63;
    if (lane == 0) rd[wid] = local;
    __syncthreads();
    if (tid < 64) {
        double v = (tid < 16) ? rd[tid] : 0.0;
#pragma unroll
        for (int off = 8; off > 0; off >>= 1) v += __shfl_xor(v, off);
        if (tid == 0) out[0] = (float)(v * (-1.0 / (double)NROWS));
    }
}

extern "C" void kernel_launch(void* const* d_in, const int* in_sizes, int n_in,
                              void* d_out, int out_size, void* d_ws, size_t ws_size,
                              hipStream_t stream)
{
    const float* pred  = (const float*)d_in[0];
    const int* target  = (const int*)d_in[1];
    float* out         = (float*)d_out;

    float* focal = (float*)d_ws;   // 4096 floats

    focal_kernel<<<NROWS, BLK, 0, stream>>>(pred, focal);
    finalize_kernel<<<1, 1024, 0, stream>>>(target, focal, out);
}